// Round 3
// baseline (314.134 us; speedup 1.0000x reference)
//
#include <hip/hip_runtime.h>
#include <cstdint>
#include <cstddef>

// ---------------------------------------------------------------------------
// Hgru2 (GLA-style gated linear attention), B=4, N=2048, d=1024, h=8, hd=128
//   cast x,W -> bf16
//   gemm_qkv: Q=silu(xWq^T), f=sigmoid(xWk^T) -> K=1-f (bf16), G=logsigmoid(f) (f32), V (bf16)
//   phaseA  : cumsum b; U^T[v][i] = sum_s V*k*exp(bC-b_s); D=exp(bC);
//             in-place Q<-q*exp(b), K<-k*exp(-b)   (moves all exp out of phaseC)
//   phaseC  : O = tril(Qh Kt^T) V + Qh S,  S ~= U_{c-1} + D_{c-1} U_{c-2}
//   rmsnorm -> bf16;  gemm_out: out = normed @ Wo^T (f32)
// R3: GEMM K-loop addresses made loop-invariant (4 ds_read VGPR bases + const
//     offsets; 1 staging voffset + SGPR-uniform column step) to kill the VALU
//     bottleneck (R2: VALUBusy 51% vs MfmaUtil 18.7%).
// ---------------------------------------------------------------------------

typedef unsigned short u16;
using f32x4  = __attribute__((ext_vector_type(4))) float;
using bf16x8 = __attribute__((ext_vector_type(8))) short;

__device__ __forceinline__ float bf2f(u16 u) {
  union { unsigned int i; float f; } v; v.i = ((unsigned int)u) << 16; return v.f;
}
__device__ __forceinline__ u16 f2bf(float f) {
  union { float f; unsigned int i; } v; v.f = f;
  unsigned int r = v.i + 0x7fffu + ((v.i >> 16) & 1u);
  return (u16)(r >> 16);
}
__device__ __forceinline__ void async_load16(const void* g, void* l) {
  __builtin_amdgcn_global_load_lds(
      (const __attribute__((address_space(1))) unsigned int*)(uintptr_t)g,
      (__attribute__((address_space(3))) unsigned int*)(uintptr_t)l, 16, 0, 0);
}

// ---------------------------------------------------------------------------
// 128x128-tile bf16 GEMM core, C = A * B^T, A/B row-major with ld=1024, K=1024.
// 256 threads = 4 waves; 16x(16x16x32) MFMA per wave per K-step; BK=64,
// double-buffered in one 64KB LDS block; k-group XOR-swizzled by (row&7).
// All K-loop addresses are loop-invariant VGPRs + constant immediates.
// ---------------------------------------------------------------------------
__device__ __forceinline__ void gemm128_core(const u16* __restrict__ Ag, const u16* __restrict__ Bg,
                                             u16* smem, f32x4 (&acc)[4][4]) {
  const int tid = threadIdx.x;
  const int lane = tid & 63, wave = tid >> 6;
  const int wm = (wave & 1) * 64, wn = (wave >> 1) * 64;
  const int r = lane & 15, quad = lane >> 4;
  const int xk = r & 7;
  // ds_read bases (elements); buffer swap (+16384) and i-step (+1024) are immediates
  const u16* baseA0 = smem + (wm + r) * 64 + ((quad ^ xk) & 7) * 8;
  const u16* baseA1 = smem + (wm + r) * 64 + (((quad + 4) ^ xk) & 7) * 8;
  const u16* baseB0 = smem + 8192 + (wn + r) * 64 + ((quad ^ xk) & 7) * 8;
  const u16* baseB1 = smem + 8192 + (wn + r) * 64 + (((quad + 4) ^ xk) & 7) * 8;
  // staging: per-lane invariant source offset (row*1024 + g*8); it/kt parts uniform
  const int soff = (tid >> 3) * 1024 + (((tid & 7) ^ ((tid >> 3) & 7)) * 8);
  u16* dA = smem + wave * 512;          // + it*2048 + buf*16384
  u16* dB = smem + 8192 + wave * 512;
#pragma unroll
  for (int it = 0; it < 4; ++it) {
    async_load16(Ag + it * 32768 + soff, dA + it * 2048);
    async_load16(Bg + it * 32768 + soff, dB + it * 2048);
  }
#pragma unroll 2
  for (int kt = 0; kt < 16; ++kt) {
    const int cb = (kt & 1) * 16384;
    __syncthreads();                     // drains cur-buffer loads (issued 1 phase ago)
    if (kt < 15) {
      const int nb = ((kt + 1) & 1) * 16384;
      const u16* As = Ag + (kt + 1) * 64;
      const u16* Bs = Bg + (kt + 1) * 64;
#pragma unroll
      for (int it = 0; it < 4; ++it) {
        async_load16(As + it * 32768 + soff, dA + nb + it * 2048);
        async_load16(Bs + it * 32768 + soff, dB + nb + it * 2048);
      }
    }
    bf16x8 af[4], bv[4];
#pragma unroll
    for (int i = 0; i < 4; ++i) af[i] = *(const bf16x8*)(baseA0 + cb + i * 1024);
#pragma unroll
    for (int j = 0; j < 4; ++j) bv[j] = *(const bf16x8*)(baseB0 + cb + j * 1024);
#pragma unroll
    for (int i = 0; i < 4; ++i)
#pragma unroll
      for (int j = 0; j < 4; ++j)
        acc[i][j] = __builtin_amdgcn_mfma_f32_16x16x32_bf16(af[i], bv[j], acc[i][j], 0, 0, 0);
#pragma unroll
    for (int i = 0; i < 4; ++i) af[i] = *(const bf16x8*)(baseA1 + cb + i * 1024);
#pragma unroll
    for (int j = 0; j < 4; ++j) bv[j] = *(const bf16x8*)(baseB1 + cb + j * 1024);
#pragma unroll
    for (int i = 0; i < 4; ++i)
#pragma unroll
      for (int j = 0; j < 4; ++j)
        acc[i][j] = __builtin_amdgcn_mfma_f32_16x16x32_bf16(af[i], bv[j], acc[i][j], 0, 0, 0);
  }
}

// ---------------------------------------------------------------------------
__global__ __launch_bounds__(256) void cast_f32_bf16(const float* __restrict__ src,
                                                     u16* __restrict__ dst, int n4) {
  int i = blockIdx.x * 256 + threadIdx.x;
  if (i >= n4) return;
  float4 v = ((const float4*)src)[i];
  unsigned int lo = (unsigned)f2bf(v.x) | ((unsigned)f2bf(v.y) << 16);
  unsigned int hi = (unsigned)f2bf(v.z) | ((unsigned)f2bf(v.w) << 16);
  ((uint2*)dst)[i] = make_uint2(lo, hi);
}

__global__ __launch_bounds__(256) void cast_w4(const float* __restrict__ w0, const float* __restrict__ w1,
                                               const float* __restrict__ w2, const float* __restrict__ w3,
                                               u16* __restrict__ d0, u16* __restrict__ d1,
                                               u16* __restrict__ d2, u16* __restrict__ d3) {
  const float* src = blockIdx.y == 0 ? w0 : (blockIdx.y == 1 ? w1 : (blockIdx.y == 2 ? w2 : w3));
  u16* dst = blockIdx.y == 0 ? d0 : (blockIdx.y == 1 ? d1 : (blockIdx.y == 2 ? d2 : d3));
  int i = blockIdx.x * 256 + threadIdx.x;
  float4 v = ((const float4*)src)[i];
  unsigned int lo = (unsigned)f2bf(v.x) | ((unsigned)f2bf(v.y) << 16);
  unsigned int hi = (unsigned)f2bf(v.z) | ((unsigned)f2bf(v.w) << 16);
  ((uint2*)dst)[i] = make_uint2(lo, hi);
}

// grid (64, 24): y/8 selects {Q,K,V}, y&7 = 128-col block
__global__ __launch_bounds__(256) void hgru_gemm_qkv(
    const u16* __restrict__ Xb, const u16* __restrict__ Wqb, const u16* __restrict__ Wkb,
    const u16* __restrict__ Wvb, u16* __restrict__ Qb, u16* __restrict__ Kb,
    float* __restrict__ G, u16* __restrict__ Vb) {
  __shared__ alignas(16) u16 smem[32768];
  const int which = blockIdx.y >> 3, bn = blockIdx.y & 7;
  const u16* W = which == 0 ? Wqb : (which == 1 ? Wkb : Wvb);
  const u16* Ag = Xb + (size_t)blockIdx.x * 128 * 1024;
  const u16* Bg = W + (size_t)bn * 128 * 1024;
  f32x4 acc[4][4] = {};
  gemm128_core(Ag, Bg, smem, acc);
  const int tid = threadIdx.x, lane = tid & 63, wave = tid >> 6;
  const int wm = (wave & 1) * 64, wn = (wave >> 1) * 64;
  const int r = lane & 15, quad = lane >> 4;
#pragma unroll
  for (int i = 0; i < 4; ++i)
#pragma unroll
    for (int j = 0; j < 4; ++j)
#pragma unroll
      for (int reg = 0; reg < 4; ++reg) {
        int m = blockIdx.x * 128 + wm + i * 16 + quad * 4 + reg;
        int n = bn * 128 + wn + j * 16 + r;
        size_t off = (size_t)m * 1024 + n;
        float z = acc[i][j][reg];
        if (which == 0) {
          Qb[off] = f2bf(z / (1.f + __expf(-z)));      // silu
        } else if (which == 1) {
          float ek = __expf(-z);
          float fs = 1.f / (1.f + ek);                  // f = sigmoid(z)
          Kb[off] = f2bf(ek * fs);                      // k = 1 - f
          G[off] = -log1pf(__expf(-fs));                // log_sigmoid(f)
        } else {
          Vb[off] = f2bf(z);
        }
      }
}

// phaseA: grid 2048 = (b*8+h)*64 + c.
// outputs: U^T[v][i] bf16, D[i]=exp(b31) f32, Q<-q*exp(b) in place, K<-k*exp(-b) in place
__global__ __launch_bounds__(256) void hgru_phaseA(
    u16* __restrict__ Qb, u16* __restrict__ Kb, const u16* __restrict__ Vb,
    const float* __restrict__ G, u16* __restrict__ SU, float* __restrict__ Dd) {
  __shared__ alignas(16) float sb[32 * 128];
  __shared__ float sD[128];
  __shared__ alignas(16) u16 sKt[128 * 40];    // khat^T [i][s]
  __shared__ alignas(16) u16 sVt[128 * 40];    // V^T    [v][s]
  const int tid = threadIdx.x, blk = blockIdx.x;
  const int c = blk & 63, bh = blk >> 6, h = bh & 7, b = bh >> 3;
  const size_t rowbase = (size_t)(b * 2048 + c * 32) * 1024 + h * 128;

  // 2-phase parallel cumsum: 256 threads = 128 cols x 2 row-halves
  {
    const int col = tid & 127, half = tid >> 7;
    float run = 0.f;
    const size_t gbase = rowbase + (size_t)(half * 16) * 1024 + col;
#pragma unroll
    for (int t = 0; t < 16; ++t) {
      run += G[gbase + (size_t)t * 1024];
      sb[(half * 16 + t) * 128 + col] = run;
    }
  }
  __syncthreads();
  {
    const int col = tid & 127;
    if (tid >> 7) {
      float fix = sb[15 * 128 + col];
#pragma unroll
      for (int t = 16; t < 32; ++t) sb[t * 128 + col] += fix;
    }
  }
  __syncthreads();
  if (tid < 128) {
    float d = __expf(sb[31 * 128 + tid]);
    sD[tid] = d;
    Dd[(size_t)blk * 128 + tid] = d;
  }
  __syncthreads();
#pragma unroll
  for (int kq = 0; kq < 16; ++kq) {
    int idx = kq * 256 + tid;           // [s][i]
    int s = idx >> 7, i = idx & 127;
    size_t off = rowbase + (size_t)s * 1024 + i;
    float bb = sb[s * 128 + i];
    float en = __expf(-bb);
    float ep = __expf(bb);
    float kv = bf2f(Kb[off]);
    float qv = bf2f(Qb[off]);
    float ktil = kv * en;               // k*exp(-b_s)
    Kb[off] = f2bf(ktil);
    Qb[off] = f2bf(qv * ep);
    sKt[i * 40 + s] = f2bf(ktil * sD[i]);  // k*exp(bC-b_s)
    sVt[i * 40 + s] = Vb[off];
  }
  __syncthreads();
  const int lane = tid & 63, wave = tid >> 6;
  const int wm = (wave & 1) * 64, wn = (wave >> 1) * 64;
  const int r = lane & 15, quad = lane >> 4;
  f32x4 acc[4][4] = {};
  bf16x8 af[4], bv[4];
#pragma unroll
  for (int i = 0; i < 4; ++i) af[i] = *(const bf16x8*)(sVt + (wm + i * 16 + r) * 40 + quad * 8);
#pragma unroll
  for (int j = 0; j < 4; ++j) bv[j] = *(const bf16x8*)(sKt + (wn + j * 16 + r) * 40 + quad * 8);
#pragma unroll
  for (int i = 0; i < 4; ++i)
#pragma unroll
    for (int j = 0; j < 4; ++j)
      acc[i][j] = __builtin_amdgcn_mfma_f32_16x16x32_bf16(af[i], bv[j], acc[i][j], 0, 0, 0);
  u16* SUo = SU + (size_t)blk * 16384;
#pragma unroll
  for (int i = 0; i < 4; ++i)
#pragma unroll
    for (int j = 0; j < 4; ++j)
#pragma unroll
      for (int reg = 0; reg < 4; ++reg) {
        int v = wm + i * 16 + quad * 4 + reg;
        int ii = wn + j * 16 + r;
        SUo[v * 128 + ii] = f2bf(acc[i][j][reg]);
      }
}

// phaseC smem (bytes): sQ[0,8704) sVt[8704,18944) sAm[18944,21504)
// union at 21504: { sK 8704 } | { sSt u16 128x136 = 34816 } ; total 56320
__global__ __launch_bounds__(256) void hgru_phaseC(
    const u16* __restrict__ Qh, const u16* __restrict__ Kt, const u16* __restrict__ Vb,
    const u16* __restrict__ SU, const float* __restrict__ Dd, u16* __restrict__ O) {
  __shared__ alignas(16) char smem[56320];
  u16* sQ  = (u16*)(smem);                // Qh [t][136]
  u16* sVt = (u16*)(smem + 8704);         // V^T [v][40]
  u16* sAm = (u16*)(smem + 18944);        // masked A [t][40]
  u16* sK  = (u16*)(smem + 21504);        // Kt [t][136]
  u16* sSt = (u16*)(smem + 21504);        // S^(c) [v][136] (after GEMM1)
  const int tid = threadIdx.x, blk = blockIdx.x;
  const int c = blk & 63, bh = blk >> 6, h = bh & 7, b = bh >> 3;
  const size_t rowbase = (size_t)(b * 2048 + c * 32) * 1024 + h * 128;

  // stage Qh/Kt vectorized (bf16x8)
#pragma unroll
  for (int kq = 0; kq < 2; ++kq) {
    int idx = kq * 256 + tid;
    int t = idx >> 4, j8 = idx & 15;
    size_t off = rowbase + (size_t)t * 1024 + j8 * 8;
    uint4 q = *(const uint4*)(Qh + off);
    uint4 k = *(const uint4*)(Kt + off);
    *(uint4*)(sQ + t * 136 + j8 * 8) = q;
    *(uint4*)(sK + t * 136 + j8 * 8) = k;
  }
#pragma unroll
  for (int kq = 0; kq < 16; ++kq) {
    int idx = kq * 256 + tid;           // [s][v] -> [v][s]
    int s = idx >> 7, v = idx & 127;
    sVt[v * 40 + s] = Vb[rowbase + (size_t)s * 1024 + v];
  }
  __syncthreads();
  const int lane = tid & 63, wave = tid >> 6;
  const int r = lane & 15, quad = lane >> 4;
  // GEMM1: A = Qh Kt^T (32x32, K=128): A[t][s] = q_t k_s exp(b_t - b_s)
  {
    const int mi = wave & 1, nj = wave >> 1;
    f32x4 a1 = {0.f, 0.f, 0.f, 0.f};
#pragma unroll
    for (int ks = 0; ks < 4; ++ks) {
      bf16x8 af = *(const bf16x8*)(sQ + (mi * 16 + r) * 136 + ks * 32 + quad * 8);
      bf16x8 bk = *(const bf16x8*)(sK + (nj * 16 + r) * 136 + ks * 32 + quad * 8);
      a1 = __builtin_amdgcn_mfma_f32_16x16x32_bf16(af, bk, a1, 0, 0, 0);
    }
    __syncthreads();  // all sK reads done before sSt overwrite
#pragma unroll
    for (int reg = 0; reg < 4; ++reg) {
      int t = mi * 16 + quad * 4 + reg;
      int s = nj * 16 + r;
      sAm[t * 40 + s] = (s <= t) ? f2bf(a1[reg]) : (u16)0;
    }
  }
  // stage S^(c) ~= U_{c-1} + D_{c-1} * U_{c-2}
  {
    const int c1 = (c >= 1) ? c - 1 : 0;
    const int c2 = (c >= 2) ? c - 2 : 0;
    const u16* U1 = SU + (size_t)(bh * 64 + c1) * 16384;
    const u16* U2 = SU + (size_t)(bh * 64 + c2) * 16384;
    const float* D1 = Dd + (size_t)(bh * 64 + c1) * 128;
#pragma unroll
    for (int g8 = 0; g8 < 8; ++g8) {
      int idx = g8 * 256 + tid;
      int v = idx >> 4, ic = idx & 15;
      float vals[8];
#pragma unroll
      for (int e = 0; e < 8; ++e) vals[e] = 0.f;
      if (c >= 1) {
        uint4 raw = *(const uint4*)(U1 + v * 128 + ic * 8);
        vals[0] = bf2f((u16)(raw.x & 0xffff)); vals[1] = bf2f((u16)(raw.x >> 16));
        vals[2] = bf2f((u16)(raw.y & 0xffff)); vals[3] = bf2f((u16)(raw.y >> 16));
        vals[4] = bf2f((u16)(raw.z & 0xffff)); vals[5] = bf2f((u16)(raw.z >> 16));
        vals[6] = bf2f((u16)(raw.w & 0xffff)); vals[7] = bf2f((u16)(raw.w >> 16));
      }
      if (c >= 2) {
        uint4 raw = *(const uint4*)(U2 + v * 128 + ic * 8);
        float4 da = ((const float4*)D1)[ic * 2];
        float4 db = ((const float4*)D1)[ic * 2 + 1];
        vals[0] += da.x * bf2f((u16)(raw.x & 0xffff)); vals[1] += da.y * bf2f((u16)(raw.x >> 16));
        vals[2] += da.z * bf2f((u16)(raw.y & 0xffff)); vals[3] += da.w * bf2f((u16)(raw.y >> 16));
        vals[4] += db.x * bf2f((u16)(raw.z & 0xffff)); vals[5] += db.y * bf2f((u16)(raw.z >> 16));
        vals[6] += db.z * bf2f((u16)(raw.w & 0xffff)); vals[7] += db.w * bf2f((u16)(raw.w >> 16));
      }
      uint4 o;
      o.x = (unsigned)f2bf(vals[0]) | ((unsigned)f2bf(vals[1]) << 16);
      o.y = (unsigned)f2bf(vals[2]) | ((unsigned)f2bf(vals[3]) << 16);
      o.z = (unsigned)f2bf(vals[4]) | ((unsigned)f2bf(vals[5]) << 16);
      o.w = (unsigned)f2bf(vals[6]) | ((unsigned)f2bf(vals[7]) << 16);
      *(uint4*)(sSt + v * 136 + ic * 8) = o;
    }
  }
  __syncthreads();
  // GEMM2: O[t][v] = Am V + Qh S
  f32x4 acc2[2][2] = {};
#pragma unroll
  for (int mi = 0; mi < 2; ++mi) {
    bf16x8 af = *(const bf16x8*)(sAm + (mi * 16 + r) * 40 + quad * 8);
#pragma unroll
    for (int nj = 0; nj < 2; ++nj) {
      bf16x8 bv = *(const bf16x8*)(sVt + (wave * 32 + nj * 16 + r) * 40 + quad * 8);
      acc2[mi][nj] = __builtin_amdgcn_mfma_f32_16x16x32_bf16(af, bv, acc2[mi][nj], 0, 0, 0);
    }
  }
#pragma unroll
  for (int ks = 0; ks < 4; ++ks) {
    bf16x8 afq[2], bst[2];
#pragma unroll
    for (int mi = 0; mi < 2; ++mi)
      afq[mi] = *(const bf16x8*)(sQ + (mi * 16 + r) * 136 + ks * 32 + quad * 8);
#pragma unroll
    for (int nj = 0; nj < 2; ++nj)
      bst[nj] = *(const bf16x8*)(sSt + (wave * 32 + nj * 16 + r) * 136 + ks * 32 + quad * 8);
#pragma unroll
    for (int mi = 0; mi < 2; ++mi)
#pragma unroll
      for (int nj = 0; nj < 2; ++nj)
        acc2[mi][nj] = __builtin_amdgcn_mfma_f32_16x16x32_bf16(afq[mi], bst[nj], acc2[mi][nj], 0, 0, 0);
  }
#pragma unroll
  for (int mi = 0; mi < 2; ++mi)
#pragma unroll
    for (int nj = 0; nj < 2; ++nj)
#pragma unroll
      for (int reg = 0; reg < 4; ++reg) {
        int t = mi * 16 + quad * 4 + reg;
        int v = wave * 32 + nj * 16 + r;
        O[rowbase + (size_t)t * 1024 + v] = f2bf(acc2[mi][nj][reg]);
      }
}

__global__ __launch_bounds__(256) void hgru_rmsnorm(const u16* __restrict__ O,
                                                    const float* __restrict__ w,
                                                    u16* __restrict__ On) {
  __shared__ float sred[4];
  const int row = blockIdx.x, tid = threadIdx.x;
  const size_t base = (size_t)row * 1024;
  float vals[4];
  float ss = 0.f;
#pragma unroll
  for (int k = 0; k < 4; ++k) {
    float v = bf2f(O[base + k * 256 + tid]);
    vals[k] = v;
    ss += v * v;
  }
#pragma unroll
  for (int m = 32; m >= 1; m >>= 1) ss += __shfl_xor(ss, m);
  if ((tid & 63) == 0) sred[tid >> 6] = ss;
  __syncthreads();
  float tot = sred[0] + sred[1] + sred[2] + sred[3];
  float scale = rsqrtf(tot * (1.f / 1024.f) + 1e-6f);
#pragma unroll
  for (int k = 0; k < 4; ++k)
    On[base + k * 256 + tid] = f2bf(vals[k] * scale * w[k * 256 + tid]);
}

__global__ __launch_bounds__(256) void hgru_gemm_out(const u16* __restrict__ Ab,
                                                     const u16* __restrict__ Wob,
                                                     float* __restrict__ out) {
  __shared__ alignas(16) u16 smem[32768];
  const u16* Ag = Ab + (size_t)blockIdx.x * 128 * 1024;
  const u16* Bg = Wob + (size_t)blockIdx.y * 128 * 1024;
  f32x4 acc[4][4] = {};
  gemm128_core(Ag, Bg, smem, acc);
  const int tid = threadIdx.x, lane = tid & 63, wave = tid >> 6;
  const int wm = (wave & 1) * 64, wn = (wave >> 1) * 64;
  const int r = lane & 15, quad = lane >> 4;
#pragma unroll
  for (int i = 0; i < 4; ++i)
#pragma unroll
    for (int j = 0; j < 4; ++j)
#pragma unroll
      for (int reg = 0; reg < 4; ++reg) {
        int m = blockIdx.x * 128 + wm + i * 16 + quad * 4 + reg;
        int n = blockIdx.y * 128 + wn + j * 16 + r;
        out[(size_t)m * 1024 + n] = acc[i][j][reg];
      }
}

// ---------------------------------------------------------------------------
extern "C" void kernel_launch(void* const* d_in, const int* in_sizes, int n_in,
                              void* d_out, int out_size, void* d_ws, size_t ws_size,
                              hipStream_t stream) {
  const float* x  = (const float*)d_in[0];
  const float* Wq = (const float*)d_in[1];
  const float* Wk = (const float*)d_in[2];
  const float* Wv = (const float*)d_in[3];
  const float* Wo = (const float*)d_in[4];
  const float* nw = (const float*)d_in[5];
  float* out = (float*)d_out;
  char* ws = (char*)d_ws;

  u16* Xb   = (u16*)(ws + 0);            // 16 MB (reused as normed output later)
  u16* Wqb  = (u16*)(ws + 16777216);
  u16* Wkb  = (u16*)(ws + 18874368);
  u16* Wvb  = (u16*)(ws + 20971520);
  u16* Wob  = (u16*)(ws + 23068672);
  u16* Qb   = (u16*)(ws + 25165824);     // q -> qhat in place (phaseA)
  u16* Kb   = (u16*)(ws + 41943040);     // k -> ktilde in place (phaseA)
  u16* Vb   = (u16*)(ws + 58720256);
  float* G  = (float*)(ws + 75497472);   // 32 MB
  u16* SU   = (u16*)(ws + 109051904);    // 64 MB
  float* Dd = (float*)(ws + 176160768);  // 1 MB
  u16* Obf  = (u16*)(ws + 177209344);    // 16 MB
  u16* On   = Xb;

  cast_f32_bf16<<<8192, 256, 0, stream>>>(x, Xb, 2097152);
  dim3 gw(1024, 4);
  cast_w4<<<gw, 256, 0, stream>>>(Wq, Wk, Wv, Wo, Wqb, Wkb, Wvb, Wob);

  dim3 gq(64, 24);
  hgru_gemm_qkv<<<gq, 256, 0, stream>>>(Xb, Wqb, Wkb, Wvb, Qb, Kb, G, Vb);
  hgru_phaseA<<<2048, 256, 0, stream>>>(Qb, Kb, Vb, G, SU, Dd);
  hgru_phaseC<<<2048, 256, 0, stream>>>(Qb, Kb, Vb, SU, Dd, Obf);
  hgru_rmsnorm<<<8192, 256, 0, stream>>>(Obf, nw, On);
  dim3 go(64, 8);
  hgru_gemm_out<<<go, 256, 0, stream>>>(On, Wob, out);
}

// Round 4
// 285.392 us; speedup vs baseline: 1.1007x; 1.1007x over previous
//
#include <hip/hip_runtime.h>
#include <cstdint>
#include <cstddef>

// ---------------------------------------------------------------------------
// Hgru2 (GLA-style gated linear attention), B=4, N=2048, d=1024, h=8, hd=128
//   cast x,W -> bf16
//   gemm_qkv: Q=silu(xWq^T), f=sigmoid(xWk^T) -> K=1-f (bf16), G=logsigmoid(f) (f32), V (bf16)
//   phaseA  : cumsum b; U^T[v][i] = sum_s V*k*exp(bC-b_s); D=exp(bC);
//             in-place Q<-q*exp(b), K<-k*exp(-b)
//   phaseC  : O = tril(Qh Kt^T) V + Qh S,  S ~= U_{c-1} + D_{c-1} U_{c-2}
//   rmsnorm -> bf16;  gemm_out: out = normed @ Wo^T (f32)
// R4: occupancy over intra-block pipelining — single 32KB LDS buffer,
//     m97-style 2-barrier K-loop (keeps R2 swizzle: 0 conflicts; R3 invariant
//     addrs). VGPR=88 -> 16 waves/CU cap -> 4 blocks/CU (was LDS-capped at 2).
//     Cross-block overlap hides the issue->drain latency (m97/m114 evidence).
// ---------------------------------------------------------------------------

typedef unsigned short u16;
using f32x4  = __attribute__((ext_vector_type(4))) float;
using bf16x8 = __attribute__((ext_vector_type(8))) short;

__device__ __forceinline__ float bf2f(u16 u) {
  union { unsigned int i; float f; } v; v.i = ((unsigned int)u) << 16; return v.f;
}
__device__ __forceinline__ u16 f2bf(float f) {
  union { float f; unsigned int i; } v; v.f = f;
  unsigned int r = v.i + 0x7fffu + ((v.i >> 16) & 1u);
  return (u16)(r >> 16);
}
__device__ __forceinline__ void async_load16(const void* g, void* l) {
  __builtin_amdgcn_global_load_lds(
      (const __attribute__((address_space(1))) unsigned int*)(uintptr_t)g,
      (__attribute__((address_space(3))) unsigned int*)(uintptr_t)l, 16, 0, 0);
}

// ---------------------------------------------------------------------------
// 128x128-tile bf16 GEMM core, C = A * B^T, A/B row-major with ld=1024, K=1024.
// 256 threads = 4 waves; 32 MFMA per wave per K-step; BK=64, single 32KB
// buffer, 2 barriers per K-step; k-group XOR-swizzled by (row&7), 0 conflicts.
// ---------------------------------------------------------------------------
__device__ __forceinline__ void gemm128_core(const u16* __restrict__ Ag, const u16* __restrict__ Bg,
                                             u16* smem, f32x4 (&acc)[4][4]) {
  const int tid = threadIdx.x;
  const int lane = tid & 63, wave = tid >> 6;
  const int wm = (wave & 1) * 64, wn = (wave >> 1) * 64;
  const int r = lane & 15, quad = lane >> 4;
  const int xk = r & 7;
  // ds_read bases (elements); i-step (+1024) is an immediate offset
  const u16* baseA0 = smem + (wm + r) * 64 + ((quad ^ xk) & 7) * 8;
  const u16* baseA1 = smem + (wm + r) * 64 + (((quad + 4) ^ xk) & 7) * 8;
  const u16* baseB0 = smem + 8192 + (wn + r) * 64 + ((quad ^ xk) & 7) * 8;
  const u16* baseB1 = smem + 8192 + (wn + r) * 64 + (((quad + 4) ^ xk) & 7) * 8;
  // staging: per-lane invariant source offset (row*1024 + swizzled-col*8)
  const int soff = (tid >> 3) * 1024 + (((tid & 7) ^ ((tid >> 3) & 7)) * 8);
  u16* dA = smem + wave * 512;          // + it*2048
  u16* dB = smem + 8192 + wave * 512;
  for (int kt = 0; kt < 16; ++kt) {
    __syncthreads();                    // prior compute's ds_reads complete
    const u16* As = Ag + kt * 64 + soff;
    const u16* Bs = Bg + kt * 64 + soff;
#pragma unroll
    for (int it = 0; it < 4; ++it) {
      async_load16(As + it * 32768, dA + it * 2048);
      async_load16(Bs + it * 32768, dB + it * 2048);
    }
    __syncthreads();                    // vmcnt(0) drain: staging visible
    bf16x8 af[4], bv[4];
#pragma unroll
    for (int i = 0; i < 4; ++i) af[i] = *(const bf16x8*)(baseA0 + i * 1024);
#pragma unroll
    for (int j = 0; j < 4; ++j) bv[j] = *(const bf16x8*)(baseB0 + j * 1024);
#pragma unroll
    for (int i = 0; i < 4; ++i)
#pragma unroll
      for (int j = 0; j < 4; ++j)
        acc[i][j] = __builtin_amdgcn_mfma_f32_16x16x32_bf16(af[i], bv[j], acc[i][j], 0, 0, 0);
#pragma unroll
    for (int i = 0; i < 4; ++i) af[i] = *(const bf16x8*)(baseA1 + i * 1024);
#pragma unroll
    for (int j = 0; j < 4; ++j) bv[j] = *(const bf16x8*)(baseB1 + j * 1024);
#pragma unroll
    for (int i = 0; i < 4; ++i)
#pragma unroll
      for (int j = 0; j < 4; ++j)
        acc[i][j] = __builtin_amdgcn_mfma_f32_16x16x32_bf16(af[i], bv[j], acc[i][j], 0, 0, 0);
  }
}

// ---------------------------------------------------------------------------
__global__ __launch_bounds__(256) void cast_f32_bf16(const float* __restrict__ src,
                                                     u16* __restrict__ dst, int n4) {
  int i = blockIdx.x * 256 + threadIdx.x;
  if (i >= n4) return;
  float4 v = ((const float4*)src)[i];
  unsigned int lo = (unsigned)f2bf(v.x) | ((unsigned)f2bf(v.y) << 16);
  unsigned int hi = (unsigned)f2bf(v.z) | ((unsigned)f2bf(v.w) << 16);
  ((uint2*)dst)[i] = make_uint2(lo, hi);
}

__global__ __launch_bounds__(256) void cast_w4(const float* __restrict__ w0, const float* __restrict__ w1,
                                               const float* __restrict__ w2, const float* __restrict__ w3,
                                               u16* __restrict__ d0, u16* __restrict__ d1,
                                               u16* __restrict__ d2, u16* __restrict__ d3) {
  const float* src = blockIdx.y == 0 ? w0 : (blockIdx.y == 1 ? w1 : (blockIdx.y == 2 ? w2 : w3));
  u16* dst = blockIdx.y == 0 ? d0 : (blockIdx.y == 1 ? d1 : (blockIdx.y == 2 ? d2 : d3));
  int i = blockIdx.x * 256 + threadIdx.x;
  float4 v = ((const float4*)src)[i];
  unsigned int lo = (unsigned)f2bf(v.x) | ((unsigned)f2bf(v.y) << 16);
  unsigned int hi = (unsigned)f2bf(v.z) | ((unsigned)f2bf(v.w) << 16);
  ((uint2*)dst)[i] = make_uint2(lo, hi);
}

// grid (64, 24): y/8 selects {Q,K,V}, y&7 = 128-col block
__global__ __launch_bounds__(256) void hgru_gemm_qkv(
    const u16* __restrict__ Xb, const u16* __restrict__ Wqb, const u16* __restrict__ Wkb,
    const u16* __restrict__ Wvb, u16* __restrict__ Qb, u16* __restrict__ Kb,
    float* __restrict__ G, u16* __restrict__ Vb) {
  __shared__ alignas(16) u16 smem[16384];
  const int which = blockIdx.y >> 3, bn = blockIdx.y & 7;
  const u16* W = which == 0 ? Wqb : (which == 1 ? Wkb : Wvb);
  const u16* Ag = Xb + (size_t)blockIdx.x * 128 * 1024;
  const u16* Bg = W + (size_t)bn * 128 * 1024;
  f32x4 acc[4][4] = {};
  gemm128_core(Ag, Bg, smem, acc);
  const int tid = threadIdx.x, lane = tid & 63, wave = tid >> 6;
  const int wm = (wave & 1) * 64, wn = (wave >> 1) * 64;
  const int r = lane & 15, quad = lane >> 4;
#pragma unroll
  for (int i = 0; i < 4; ++i)
#pragma unroll
    for (int j = 0; j < 4; ++j)
#pragma unroll
      for (int reg = 0; reg < 4; ++reg) {
        int m = blockIdx.x * 128 + wm + i * 16 + quad * 4 + reg;
        int n = bn * 128 + wn + j * 16 + r;
        size_t off = (size_t)m * 1024 + n;
        float z = acc[i][j][reg];
        if (which == 0) {
          Qb[off] = f2bf(z / (1.f + __expf(-z)));      // silu
        } else if (which == 1) {
          float ek = __expf(-z);
          float fs = 1.f / (1.f + ek);                  // f = sigmoid(z)
          Kb[off] = f2bf(ek * fs);                      // k = 1 - f
          G[off] = -__logf(1.f + __expf(-fs));          // log_sigmoid(f), t~0.5: no cancellation
        } else {
          Vb[off] = f2bf(z);
        }
      }
}

// phaseA: grid 2048 = (b*8+h)*64 + c.
// outputs: U^T[v][i] bf16, D[i]=exp(b31) f32, Q<-q*exp(b) in place, K<-k*exp(-b) in place
__global__ __launch_bounds__(256) void hgru_phaseA(
    u16* __restrict__ Qb, u16* __restrict__ Kb, const u16* __restrict__ Vb,
    const float* __restrict__ G, u16* __restrict__ SU, float* __restrict__ Dd) {
  __shared__ alignas(16) float sb[32 * 128];
  __shared__ float sD[128];
  __shared__ alignas(16) u16 sKt[128 * 40];    // khat^T [i][s]
  __shared__ alignas(16) u16 sVt[128 * 40];    // V^T    [v][s]
  const int tid = threadIdx.x, blk = blockIdx.x;
  const int c = blk & 63, bh = blk >> 6, h = bh & 7, b = bh >> 3;
  const size_t rowbase = (size_t)(b * 2048 + c * 32) * 1024 + h * 128;

  // 2-phase parallel cumsum: 256 threads = 128 cols x 2 row-halves
  {
    const int col = tid & 127, half = tid >> 7;
    float run = 0.f;
    const size_t gbase = rowbase + (size_t)(half * 16) * 1024 + col;
#pragma unroll
    for (int t = 0; t < 16; ++t) {
      run += G[gbase + (size_t)t * 1024];
      sb[(half * 16 + t) * 128 + col] = run;
    }
  }
  __syncthreads();
  {
    const int col = tid & 127;
    if (tid >> 7) {
      float fix = sb[15 * 128 + col];
#pragma unroll
      for (int t = 16; t < 32; ++t) sb[t * 128 + col] += fix;
    }
  }
  __syncthreads();
  if (tid < 128) {
    float d = __expf(sb[31 * 128 + tid]);
    sD[tid] = d;
    Dd[(size_t)blk * 128 + tid] = d;
  }
  __syncthreads();
#pragma unroll
  for (int kq = 0; kq < 16; ++kq) {
    int idx = kq * 256 + tid;           // [s][i]
    int s = idx >> 7, i = idx & 127;
    size_t off = rowbase + (size_t)s * 1024 + i;
    float bb = sb[s * 128 + i];
    float en = __expf(-bb);
    float ep = __expf(bb);
    float kv = bf2f(Kb[off]);
    float qv = bf2f(Qb[off]);
    float ktil = kv * en;               // k*exp(-b_s)
    Kb[off] = f2bf(ktil);
    Qb[off] = f2bf(qv * ep);
    sKt[i * 40 + s] = f2bf(ktil * sD[i]);  // k*exp(bC-b_s)
    sVt[i * 40 + s] = Vb[off];
  }
  __syncthreads();
  const int lane = tid & 63, wave = tid >> 6;
  const int wm = (wave & 1) * 64, wn = (wave >> 1) * 64;
  const int r = lane & 15, quad = lane >> 4;
  f32x4 acc[4][4] = {};
  bf16x8 af[4], bv[4];
#pragma unroll
  for (int i = 0; i < 4; ++i) af[i] = *(const bf16x8*)(sVt + (wm + i * 16 + r) * 40 + quad * 8);
#pragma unroll
  for (int j = 0; j < 4; ++j) bv[j] = *(const bf16x8*)(sKt + (wn + j * 16 + r) * 40 + quad * 8);
#pragma unroll
  for (int i = 0; i < 4; ++i)
#pragma unroll
    for (int j = 0; j < 4; ++j)
      acc[i][j] = __builtin_amdgcn_mfma_f32_16x16x32_bf16(af[i], bv[j], acc[i][j], 0, 0, 0);
  u16* SUo = SU + (size_t)blk * 16384;
#pragma unroll
  for (int i = 0; i < 4; ++i)
#pragma unroll
    for (int j = 0; j < 4; ++j)
#pragma unroll
      for (int reg = 0; reg < 4; ++reg) {
        int v = wm + i * 16 + quad * 4 + reg;
        int ii = wn + j * 16 + r;
        SUo[v * 128 + ii] = f2bf(acc[i][j][reg]);
      }
}

// phaseC smem (bytes): sQ[0,8704) sVt[8704,18944) sAm[18944,21504)
// union at 21504: { sK 8704 } | { sSt u16 128x136 = 34816 } ; total 56320
__global__ __launch_bounds__(256) void hgru_phaseC(
    const u16* __restrict__ Qh, const u16* __restrict__ Kt, const u16* __restrict__ Vb,
    const u16* __restrict__ SU, const float* __restrict__ Dd, u16* __restrict__ O) {
  __shared__ alignas(16) char smem[56320];
  u16* sQ  = (u16*)(smem);                // Qh [t][136]
  u16* sVt = (u16*)(smem + 8704);         // V^T [v][40]
  u16* sAm = (u16*)(smem + 18944);        // masked A [t][40]
  u16* sK  = (u16*)(smem + 21504);        // Kt [t][136]
  u16* sSt = (u16*)(smem + 21504);        // S^(c) [v][136] (after GEMM1)
  const int tid = threadIdx.x, blk = blockIdx.x;
  const int c = blk & 63, bh = blk >> 6, h = bh & 7, b = bh >> 3;
  const size_t rowbase = (size_t)(b * 2048 + c * 32) * 1024 + h * 128;

#pragma unroll
  for (int kq = 0; kq < 2; ++kq) {
    int idx = kq * 256 + tid;
    int t = idx >> 4, j8 = idx & 15;
    size_t off = rowbase + (size_t)t * 1024 + j8 * 8;
    uint4 q = *(const uint4*)(Qh + off);
    uint4 k = *(const uint4*)(Kt + off);
    *(uint4*)(sQ + t * 136 + j8 * 8) = q;
    *(uint4*)(sK + t * 136 + j8 * 8) = k;
  }
#pragma unroll
  for (int kq = 0; kq < 16; ++kq) {
    int idx = kq * 256 + tid;           // [s][v] -> [v][s]
    int s = idx >> 7, v = idx & 127;
    sVt[v * 40 + s] = Vb[rowbase + (size_t)s * 1024 + v];
  }
  __syncthreads();
  const int lane = tid & 63, wave = tid >> 6;
  const int r = lane & 15, quad = lane >> 4;
  // GEMM1: A = Qh Kt^T (32x32, K=128): A[t][s] = q_t k_s exp(b_t - b_s)
  {
    const int mi = wave & 1, nj = wave >> 1;
    f32x4 a1 = {0.f, 0.f, 0.f, 0.f};
#pragma unroll
    for (int ks = 0; ks < 4; ++ks) {
      bf16x8 af = *(const bf16x8*)(sQ + (mi * 16 + r) * 136 + ks * 32 + quad * 8);
      bf16x8 bk = *(const bf16x8*)(sK + (nj * 16 + r) * 136 + ks * 32 + quad * 8);
      a1 = __builtin_amdgcn_mfma_f32_16x16x32_bf16(af, bk, a1, 0, 0, 0);
    }
    __syncthreads();  // all sK reads done before sSt overwrite
#pragma unroll
    for (int reg = 0; reg < 4; ++reg) {
      int t = mi * 16 + quad * 4 + reg;
      int s = nj * 16 + r;
      sAm[t * 40 + s] = (s <= t) ? f2bf(a1[reg]) : (u16)0;
    }
  }
  // stage S^(c) ~= U_{c-1} + D_{c-1} * U_{c-2}
  {
    const int c1 = (c >= 1) ? c - 1 : 0;
    const int c2 = (c >= 2) ? c - 2 : 0;
    const u16* U1 = SU + (size_t)(bh * 64 + c1) * 16384;
    const u16* U2 = SU + (size_t)(bh * 64 + c2) * 16384;
    const float* D1 = Dd + (size_t)(bh * 64 + c1) * 128;
#pragma unroll
    for (int g8 = 0; g8 < 8; ++g8) {
      int idx = g8 * 256 + tid;
      int v = idx >> 4, ic = idx & 15;
      float vals[8];
#pragma unroll
      for (int e = 0; e < 8; ++e) vals[e] = 0.f;
      if (c >= 1) {
        uint4 raw = *(const uint4*)(U1 + v * 128 + ic * 8);
        vals[0] = bf2f((u16)(raw.x & 0xffff)); vals[1] = bf2f((u16)(raw.x >> 16));
        vals[2] = bf2f((u16)(raw.y & 0xffff)); vals[3] = bf2f((u16)(raw.y >> 16));
        vals[4] = bf2f((u16)(raw.z & 0xffff)); vals[5] = bf2f((u16)(raw.z >> 16));
        vals[6] = bf2f((u16)(raw.w & 0xffff)); vals[7] = bf2f((u16)(raw.w >> 16));
      }
      if (c >= 2) {
        uint4 raw = *(const uint4*)(U2 + v * 128 + ic * 8);
        float4 da = ((const float4*)D1)[ic * 2];
        float4 db = ((const float4*)D1)[ic * 2 + 1];
        vals[0] += da.x * bf2f((u16)(raw.x & 0xffff)); vals[1] += da.y * bf2f((u16)(raw.x >> 16));
        vals[2] += da.z * bf2f((u16)(raw.y & 0xffff)); vals[3] += da.w * bf2f((u16)(raw.y >> 16));
        vals[4] += db.x * bf2f((u16)(raw.z & 0xffff)); vals[5] += db.y * bf2f((u16)(raw.z >> 16));
        vals[6] += db.z * bf2f((u16)(raw.w & 0xffff)); vals[7] += db.w * bf2f((u16)(raw.w >> 16));
      }
      uint4 o;
      o.x = (unsigned)f2bf(vals[0]) | ((unsigned)f2bf(vals[1]) << 16);
      o.y = (unsigned)f2bf(vals[2]) | ((unsigned)f2bf(vals[3]) << 16);
      o.z = (unsigned)f2bf(vals[4]) | ((unsigned)f2bf(vals[5]) << 16);
      o.w = (unsigned)f2bf(vals[6]) | ((unsigned)f2bf(vals[7]) << 16);
      *(uint4*)(sSt + v * 136 + ic * 8) = o;
    }
  }
  __syncthreads();
  // GEMM2: O[t][v] = Am V + Qh S
  f32x4 acc2[2][2] = {};
#pragma unroll
  for (int mi = 0; mi < 2; ++mi) {
    bf16x8 af = *(const bf16x8*)(sAm + (mi * 16 + r) * 40 + quad * 8);
#pragma unroll
    for (int nj = 0; nj < 2; ++nj) {
      bf16x8 bv = *(const bf16x8*)(sVt + (wave * 32 + nj * 16 + r) * 40 + quad * 8);
      acc2[mi][nj] = __builtin_amdgcn_mfma_f32_16x16x32_bf16(af, bv, acc2[mi][nj], 0, 0, 0);
    }
  }
#pragma unroll
  for (int ks = 0; ks < 4; ++ks) {
    bf16x8 afq[2], bst[2];
#pragma unroll
    for (int mi = 0; mi < 2; ++mi)
      afq[mi] = *(const bf16x8*)(sQ + (mi * 16 + r) * 136 + ks * 32 + quad * 8);
#pragma unroll
    for (int nj = 0; nj < 2; ++nj)
      bst[nj] = *(const bf16x8*)(sSt + (wave * 32 + nj * 16 + r) * 136 + ks * 32 + quad * 8);
#pragma unroll
    for (int mi = 0; mi < 2; ++mi)
#pragma unroll
      for (int nj = 0; nj < 2; ++nj)
        acc2[mi][nj] = __builtin_amdgcn_mfma_f32_16x16x32_bf16(afq[mi], bst[nj], acc2[mi][nj], 0, 0, 0);
  }
#pragma unroll
  for (int mi = 0; mi < 2; ++mi)
#pragma unroll
    for (int nj = 0; nj < 2; ++nj)
#pragma unroll
      for (int reg = 0; reg < 4; ++reg) {
        int t = mi * 16 + quad * 4 + reg;
        int v = wave * 32 + nj * 16 + r;
        O[rowbase + (size_t)t * 1024 + v] = f2bf(acc2[mi][nj][reg]);
      }
}

__global__ __launch_bounds__(256) void hgru_rmsnorm(const u16* __restrict__ O,
                                                    const float* __restrict__ w,
                                                    u16* __restrict__ On) {
  __shared__ float sred[4];
  const int row = blockIdx.x, tid = threadIdx.x;
  const size_t base = (size_t)row * 1024;
  float vals[4];
  float ss = 0.f;
#pragma unroll
  for (int k = 0; k < 4; ++k) {
    float v = bf2f(O[base + k * 256 + tid]);
    vals[k] = v;
    ss += v * v;
  }
#pragma unroll
  for (int m = 32; m >= 1; m >>= 1) ss += __shfl_xor(ss, m);
  if ((tid & 63) == 0) sred[tid >> 6] = ss;
  __syncthreads();
  float tot = sred[0] + sred[1] + sred[2] + sred[3];
  float scale = rsqrtf(tot * (1.f / 1024.f) + 1e-6f);
#pragma unroll
  for (int k = 0; k < 4; ++k)
    On[base + k * 256 + tid] = f2bf(vals[k] * scale * w[k * 256 + tid]);
}

__global__ __launch_bounds__(256) void hgru_gemm_out(const u16* __restrict__ Ab,
                                                     const u16* __restrict__ Wob,
                                                     float* __restrict__ out) {
  __shared__ alignas(16) u16 smem[16384];
  const u16* Ag = Ab + (size_t)blockIdx.x * 128 * 1024;
  const u16* Bg = Wob + (size_t)blockIdx.y * 128 * 1024;
  f32x4 acc[4][4] = {};
  gemm128_core(Ag, Bg, smem, acc);
  const int tid = threadIdx.x, lane = tid & 63, wave = tid >> 6;
  const int wm = (wave & 1) * 64, wn = (wave >> 1) * 64;
  const int r = lane & 15, quad = lane >> 4;
#pragma unroll
  for (int i = 0; i < 4; ++i)
#pragma unroll
    for (int j = 0; j < 4; ++j)
#pragma unroll
      for (int reg = 0; reg < 4; ++reg) {
        int m = blockIdx.x * 128 + wm + i * 16 + quad * 4 + reg;
        int n = blockIdx.y * 128 + wn + j * 16 + r;
        out[(size_t)m * 1024 + n] = acc[i][j][reg];
      }
}

// ---------------------------------------------------------------------------
extern "C" void kernel_launch(void* const* d_in, const int* in_sizes, int n_in,
                              void* d_out, int out_size, void* d_ws, size_t ws_size,
                              hipStream_t stream) {
  const float* x  = (const float*)d_in[0];
  const float* Wq = (const float*)d_in[1];
  const float* Wk = (const float*)d_in[2];
  const float* Wv = (const float*)d_in[3];
  const float* Wo = (const float*)d_in[4];
  const float* nw = (const float*)d_in[5];
  float* out = (float*)d_out;
  char* ws = (char*)d_ws;

  u16* Xb   = (u16*)(ws + 0);            // 16 MB (reused as normed output later)
  u16* Wqb  = (u16*)(ws + 16777216);
  u16* Wkb  = (u16*)(ws + 18874368);
  u16* Wvb  = (u16*)(ws + 20971520);
  u16* Wob  = (u16*)(ws + 23068672);
  u16* Qb   = (u16*)(ws + 25165824);     // q -> qhat in place (phaseA)
  u16* Kb   = (u16*)(ws + 41943040);     // k -> ktilde in place (phaseA)
  u16* Vb   = (u16*)(ws + 58720256);
  float* G  = (float*)(ws + 75497472);   // 32 MB
  u16* SU   = (u16*)(ws + 109051904);    // 64 MB
  float* Dd = (float*)(ws + 176160768);  // 1 MB
  u16* Obf  = (u16*)(ws + 177209344);    // 16 MB
  u16* On   = Xb;

  cast_f32_bf16<<<8192, 256, 0, stream>>>(x, Xb, 2097152);
  dim3 gw(1024, 4);
  cast_w4<<<gw, 256, 0, stream>>>(Wq, Wk, Wv, Wo, Wqb, Wkb, Wvb, Wob);

  dim3 gq(64, 24);
  hgru_gemm_qkv<<<gq, 256, 0, stream>>>(Xb, Wqb, Wkb, Wvb, Qb, Kb, G, Vb);
  hgru_phaseA<<<2048, 256, 0, stream>>>(Qb, Kb, Vb, G, SU, Dd);
  hgru_phaseC<<<2048, 256, 0, stream>>>(Qb, Kb, Vb, SU, Dd, Obf);
  hgru_rmsnorm<<<8192, 256, 0, stream>>>(Obf, nw, On);
  dim3 go(64, 8);
  hgru_gemm_out<<<go, 256, 0, stream>>>(On, Wob, out);
}

// Round 5
// 261.027 us; speedup vs baseline: 1.2035x; 1.0933x over previous
//
#include <hip/hip_runtime.h>
#include <cstdint>
#include <cstddef>

// ---------------------------------------------------------------------------
// Hgru2 (GLA-style gated linear attention), B=4, N=2048, d=1024, h=8, hd=128
//   cast x,W -> bf16
//   gemm_qkv: Q=silu(xWq^T), K=1-sigmoid(xWk^T) (bf16), V (bf16)   [no G!]
//   phaseA (C=64): g=logsig(1-k) recomputed from k; cumsum b;
//       U^T[v][i] = sum_s V*k*exp(bC-b_s); in-place Q<-q*exp(b), K<-k*exp(-b)
//   phaseC (C=64): O = tril(Qh Kt^T) V + Qh S,  S = U_{c-1} (1-term: per-chunk
//       decay <= e^-20, truncation error ~2e-9 relative); S fragments read
//       directly from global (U^T row-major == MFMA B-operand layout)
//   rmsnorm -> bf16;  gemm_out: out = normed @ Wo^T (f32)
// R5: chunk 32->64 + 1-term state (SU traffic 192->64 MB, Dd dropped) and
//     G eliminated (64 MB saved; g recomputed from bf16 k, delta-g ~7e-4/step).
// ---------------------------------------------------------------------------

typedef unsigned short u16;
using f32x4  = __attribute__((ext_vector_type(4))) float;
using bf16x8 = __attribute__((ext_vector_type(8))) short;

__device__ __forceinline__ float bf2f(u16 u) {
  union { unsigned int i; float f; } v; v.i = ((unsigned int)u) << 16; return v.f;
}
__device__ __forceinline__ u16 f2bf(float f) {
  union { float f; unsigned int i; } v; v.f = f;
  unsigned int r = v.i + 0x7fffu + ((v.i >> 16) & 1u);
  return (u16)(r >> 16);
}
__device__ __forceinline__ void async_load16(const void* g, void* l) {
  __builtin_amdgcn_global_load_lds(
      (const __attribute__((address_space(1))) unsigned int*)(uintptr_t)g,
      (__attribute__((address_space(3))) unsigned int*)(uintptr_t)l, 16, 0, 0);
}

// ---------------------------------------------------------------------------
// 128x128-tile bf16 GEMM core (R4): single 32KB buffer, 2 barriers/K-step,
// XOR bank swizzle (0 conflicts), loop-invariant addressing.
// ---------------------------------------------------------------------------
__device__ __forceinline__ void gemm128_core(const u16* __restrict__ Ag, const u16* __restrict__ Bg,
                                             u16* smem, f32x4 (&acc)[4][4]) {
  const int tid = threadIdx.x;
  const int lane = tid & 63, wave = tid >> 6;
  const int wm = (wave & 1) * 64, wn = (wave >> 1) * 64;
  const int r = lane & 15, quad = lane >> 4;
  const int xk = r & 7;
  const u16* baseA0 = smem + (wm + r) * 64 + ((quad ^ xk) & 7) * 8;
  const u16* baseA1 = smem + (wm + r) * 64 + (((quad + 4) ^ xk) & 7) * 8;
  const u16* baseB0 = smem + 8192 + (wn + r) * 64 + ((quad ^ xk) & 7) * 8;
  const u16* baseB1 = smem + 8192 + (wn + r) * 64 + (((quad + 4) ^ xk) & 7) * 8;
  const int soff = (tid >> 3) * 1024 + (((tid & 7) ^ ((tid >> 3) & 7)) * 8);
  u16* dA = smem + wave * 512;
  u16* dB = smem + 8192 + wave * 512;
  for (int kt = 0; kt < 16; ++kt) {
    __syncthreads();
    const u16* As = Ag + kt * 64 + soff;
    const u16* Bs = Bg + kt * 64 + soff;
#pragma unroll
    for (int it = 0; it < 4; ++it) {
      async_load16(As + it * 32768, dA + it * 2048);
      async_load16(Bs + it * 32768, dB + it * 2048);
    }
    __syncthreads();
    bf16x8 af[4], bv[4];
#pragma unroll
    for (int i = 0; i < 4; ++i) af[i] = *(const bf16x8*)(baseA0 + i * 1024);
#pragma unroll
    for (int j = 0; j < 4; ++j) bv[j] = *(const bf16x8*)(baseB0 + j * 1024);
#pragma unroll
    for (int i = 0; i < 4; ++i)
#pragma unroll
      for (int j = 0; j < 4; ++j)
        acc[i][j] = __builtin_amdgcn_mfma_f32_16x16x32_bf16(af[i], bv[j], acc[i][j], 0, 0, 0);
#pragma unroll
    for (int i = 0; i < 4; ++i) af[i] = *(const bf16x8*)(baseA1 + i * 1024);
#pragma unroll
    for (int j = 0; j < 4; ++j) bv[j] = *(const bf16x8*)(baseB1 + j * 1024);
#pragma unroll
    for (int i = 0; i < 4; ++i)
#pragma unroll
      for (int j = 0; j < 4; ++j)
        acc[i][j] = __builtin_amdgcn_mfma_f32_16x16x32_bf16(af[i], bv[j], acc[i][j], 0, 0, 0);
  }
}

// ---------------------------------------------------------------------------
__global__ __launch_bounds__(256) void cast_f32_bf16(const float* __restrict__ src,
                                                     u16* __restrict__ dst, int n4) {
  int i = blockIdx.x * 256 + threadIdx.x;
  if (i >= n4) return;
  float4 v = ((const float4*)src)[i];
  unsigned int lo = (unsigned)f2bf(v.x) | ((unsigned)f2bf(v.y) << 16);
  unsigned int hi = (unsigned)f2bf(v.z) | ((unsigned)f2bf(v.w) << 16);
  ((uint2*)dst)[i] = make_uint2(lo, hi);
}

__global__ __launch_bounds__(256) void cast_w4(const float* __restrict__ w0, const float* __restrict__ w1,
                                               const float* __restrict__ w2, const float* __restrict__ w3,
                                               u16* __restrict__ d0, u16* __restrict__ d1,
                                               u16* __restrict__ d2, u16* __restrict__ d3) {
  const float* src = blockIdx.y == 0 ? w0 : (blockIdx.y == 1 ? w1 : (blockIdx.y == 2 ? w2 : w3));
  u16* dst = blockIdx.y == 0 ? d0 : (blockIdx.y == 1 ? d1 : (blockIdx.y == 2 ? d2 : d3));
  int i = blockIdx.x * 256 + threadIdx.x;
  float4 v = ((const float4*)src)[i];
  unsigned int lo = (unsigned)f2bf(v.x) | ((unsigned)f2bf(v.y) << 16);
  unsigned int hi = (unsigned)f2bf(v.z) | ((unsigned)f2bf(v.w) << 16);
  ((uint2*)dst)[i] = make_uint2(lo, hi);
}

// grid (64, 24): y/8 selects {Q,K,V}, y&7 = 128-col block
__global__ __launch_bounds__(256) void hgru_gemm_qkv(
    const u16* __restrict__ Xb, const u16* __restrict__ Wqb, const u16* __restrict__ Wkb,
    const u16* __restrict__ Wvb, u16* __restrict__ Qb, u16* __restrict__ Kb,
    u16* __restrict__ Vb) {
  __shared__ alignas(16) u16 smem[16384];
  const int which = blockIdx.y >> 3, bn = blockIdx.y & 7;
  const u16* W = which == 0 ? Wqb : (which == 1 ? Wkb : Wvb);
  const u16* Ag = Xb + (size_t)blockIdx.x * 128 * 1024;
  const u16* Bg = W + (size_t)bn * 128 * 1024;
  f32x4 acc[4][4] = {};
  gemm128_core(Ag, Bg, smem, acc);
  const int tid = threadIdx.x, lane = tid & 63, wave = tid >> 6;
  const int wm = (wave & 1) * 64, wn = (wave >> 1) * 64;
  const int r = lane & 15, quad = lane >> 4;
#pragma unroll
  for (int i = 0; i < 4; ++i)
#pragma unroll
    for (int j = 0; j < 4; ++j)
#pragma unroll
      for (int reg = 0; reg < 4; ++reg) {
        int m = blockIdx.x * 128 + wm + i * 16 + quad * 4 + reg;
        int n = bn * 128 + wn + j * 16 + r;
        size_t off = (size_t)m * 1024 + n;
        float z = acc[i][j][reg];
        if (which == 0) {
          Qb[off] = f2bf(z / (1.f + __expf(-z)));      // silu
        } else if (which == 1) {
          float ek = __expf(-z);
          Kb[off] = f2bf(ek / (1.f + ek));              // k = 1 - sigmoid(z)
        } else {
          Vb[off] = f2bf(z);
        }
      }
}

// phaseA: grid 1024 = (b*8+h)*32 + c, chunk C=64.
// outputs: U^T[v][i] bf16 (32KB/blk); Q<-q*exp(b), K<-k*exp(-b) in place.
__global__ __launch_bounds__(256) void hgru_phaseA(
    u16* __restrict__ Qb, u16* __restrict__ Kb, const u16* __restrict__ Vb,
    u16* __restrict__ SU) {
  __shared__ alignas(16) float sb[64 * 129];    // cumsum, stride 129 (bank-spread)
  __shared__ float sD[128];
  __shared__ alignas(16) u16 sKt[128 * 72];     // khat^T [i][s]
  __shared__ alignas(16) u16 sVt[128 * 72];     // V^T    [v][s]
  const int tid = threadIdx.x, blk = blockIdx.x;
  const int c = blk & 31, bh = blk >> 5, h = bh & 7, b = bh >> 3;
  const size_t rowbase = (size_t)(b * 2048 + c * 64) * 1024 + h * 128;

  // cumsum of g over 64 rows; g = logsigmoid(f), f = 1-k (recomputed from k)
  {
    const int col = tid & 127, half = tid >> 7;
    const size_t gb = rowbase + (size_t)(half * 32) * 1024 + col;
    float run = 0.f;
#pragma unroll
    for (int t = 0; t < 32; ++t) {
      float kv = bf2f(Kb[gb + (size_t)t * 1024]);
      float f = 1.f - kv;
      run -= __logf(1.f + __expf(-f));
      sb[(half * 32 + t) * 129 + col] = run;
    }
  }
  __syncthreads();
  {
    const int col = tid & 127;
    if (tid >> 7) {
      float fix = sb[31 * 129 + col];
#pragma unroll
      for (int t = 32; t < 64; ++t) sb[t * 129 + col] += fix;
    }
  }
  __syncthreads();
  if (tid < 128) sD[tid] = __expf(sb[63 * 129 + tid]);
  __syncthreads();
  // transform + transposes; lanes vary s (LDS scatter spreads all 32 banks;
  // global uint4 at 2KB stride — lines re-touched 4x via L1)
#pragma unroll
  for (int kq = 0; kq < 4; ++kq) {
    int idx = kq * 256 + tid;
    int s = idx & 63, i8 = idx >> 6;           // i8 in 0..15
    size_t off = rowbase + (size_t)s * 1024 + i8 * 8;
    uint4 qr = *(const uint4*)(Qb + off);
    uint4 kr = *(const uint4*)(Kb + off);
    uint4 vr = *(const uint4*)(Vb + off);
    const u16* qp = (const u16*)&qr;
    const u16* kp = (const u16*)&kr;
    const u16* vp = (const u16*)&vr;
    u16 qo[8], ko[8];
#pragma unroll
    for (int e = 0; e < 8; ++e) {
      int i = i8 * 8 + e;
      float bb = sb[s * 129 + i];
      float ep = __expf(bb), en = __expf(-bb);
      float ktil = bf2f(kp[e]) * en;            // k*exp(-b_s)
      qo[e] = f2bf(bf2f(qp[e]) * ep);
      ko[e] = f2bf(ktil);
      sKt[i * 72 + s] = f2bf(ktil * sD[i]);     // k*exp(bC-b_s)
      sVt[i * 72 + s] = vp[e];
    }
    *(uint4*)(Qb + off) = *(const uint4*)qo;
    *(uint4*)(Kb + off) = *(const uint4*)ko;
  }
  __syncthreads();
  // U^T[v][i] = sum_s V^T[v][s] * khat^T[i][s]; 128x128, K=64
  const int lane = tid & 63, wave = tid >> 6;
  const int wm = (wave & 1) * 64, wn = (wave >> 1) * 64;
  const int r = lane & 15, quad = lane >> 4;
  f32x4 acc[4][4] = {};
#pragma unroll
  for (int ks = 0; ks < 2; ++ks) {
    bf16x8 af[4], bv[4];
#pragma unroll
    for (int i = 0; i < 4; ++i) af[i] = *(const bf16x8*)(sVt + (wm + i * 16 + r) * 72 + ks * 32 + quad * 8);
#pragma unroll
    for (int j = 0; j < 4; ++j) bv[j] = *(const bf16x8*)(sKt + (wn + j * 16 + r) * 72 + ks * 32 + quad * 8);
#pragma unroll
    for (int i = 0; i < 4; ++i)
#pragma unroll
      for (int j = 0; j < 4; ++j)
        acc[i][j] = __builtin_amdgcn_mfma_f32_16x16x32_bf16(af[i], bv[j], acc[i][j], 0, 0, 0);
  }
  u16* SUo = SU + (size_t)blk * 16384;
#pragma unroll
  for (int i = 0; i < 4; ++i)
#pragma unroll
    for (int j = 0; j < 4; ++j)
#pragma unroll
      for (int reg = 0; reg < 4; ++reg) {
        int v = wm + i * 16 + quad * 4 + reg;
        int ii = wn + j * 16 + r;
        SUo[v * 128 + ii] = f2bf(acc[i][j][reg]);
      }
}

// phaseC: grid 1024, chunk C=64. O = tril(Qh Kt^T) V + Qh S, S = U_{c-1}.
// LDS 62.4 KB -> 2 blocks/CU; one barrier (sAm trick: GEMM2 A-fragments read
// only rows this wave wrote in GEMM1).
__global__ __launch_bounds__(256) void hgru_phaseC(
    const u16* __restrict__ Qh, const u16* __restrict__ Kt, const u16* __restrict__ Vb,
    const u16* __restrict__ SU, u16* __restrict__ O) {
  __shared__ alignas(16) u16 sQ[64 * 136];     // Qh [t][136]
  __shared__ alignas(16) u16 sK[64 * 136];     // Kt [t][136]
  __shared__ alignas(16) u16 sVt[128 * 72];    // V^T [v][s]
  __shared__ alignas(16) u16 sAm[64 * 72];     // masked A [t][s]
  const int tid = threadIdx.x, blk = blockIdx.x;
  const int c = blk & 31, bh = blk >> 5, h = bh & 7, b = bh >> 3;
  const size_t rowbase = (size_t)(b * 2048 + c * 64) * 1024 + h * 128;

  // stage Qh/Kt row-major (coalesced uint4)
#pragma unroll
  for (int kq = 0; kq < 4; ++kq) {
    int idx = kq * 256 + tid;
    int t = idx >> 4, j8 = idx & 15;
    size_t off = rowbase + (size_t)t * 1024 + j8 * 8;
    *(uint4*)(sQ + t * 136 + j8 * 8) = *(const uint4*)(Qh + off);
    *(uint4*)(sK + t * 136 + j8 * 8) = *(const uint4*)(Kt + off);
  }
  // stage V^T (lanes vary t: conflict-free scatter)
#pragma unroll
  for (int kq = 0; kq < 4; ++kq) {
    int idx = kq * 256 + tid;
    int t = idx & 63, v8 = idx >> 6;
    uint4 vr = *(const uint4*)(Vb + rowbase + (size_t)t * 1024 + v8 * 8);
    const u16* vp = (const u16*)&vr;
#pragma unroll
    for (int e = 0; e < 8; ++e) sVt[(v8 * 8 + e) * 72 + t] = vp[e];
  }
  __syncthreads();
  const int lane = tid & 63, wave = tid >> 6;
  const int r = lane & 15, quad = lane >> 4;
  // GEMM1: A = Qh Kt^T (64x64, K=128); wave w -> rows 16w..16w+15
  {
    f32x4 a1[4] = {};
#pragma unroll
    for (int ks = 0; ks < 4; ++ks) {
      bf16x8 af = *(const bf16x8*)(sQ + (wave * 16 + r) * 136 + ks * 32 + quad * 8);
#pragma unroll
      for (int nj = 0; nj < 4; ++nj) {
        bf16x8 bk = *(const bf16x8*)(sK + (nj * 16 + r) * 136 + ks * 32 + quad * 8);
        a1[nj] = __builtin_amdgcn_mfma_f32_16x16x32_bf16(af, bk, a1[nj], 0, 0, 0);
      }
    }
#pragma unroll
    for (int nj = 0; nj < 4; ++nj)
#pragma unroll
      for (int reg = 0; reg < 4; ++reg) {
        int t = wave * 16 + quad * 4 + reg;
        int s = nj * 16 + r;
        sAm[t * 72 + s] = (s <= t) ? f2bf(a1[nj][reg]) : (u16)0;
      }
  }
  // GEMM2: O[t][v] = Am V + Qh S; S-fragments direct from global U_{c-1}
  const u16* U1 = SU + (size_t)(bh * 32 + (c - 1)) * 16384;
  const bool haveS = (c >= 1);
#pragma unroll
  for (int j = 0; j < 8; ++j) {
    f32x4 acc2 = {0.f, 0.f, 0.f, 0.f};
#pragma unroll
    for (int ks = 0; ks < 2; ++ks) {
      bf16x8 af = *(const bf16x8*)(sAm + (wave * 16 + r) * 72 + ks * 32 + quad * 8);
      bf16x8 bv = *(const bf16x8*)(sVt + (j * 16 + r) * 72 + ks * 32 + quad * 8);
      acc2 = __builtin_amdgcn_mfma_f32_16x16x32_bf16(af, bv, acc2, 0, 0, 0);
    }
    if (haveS) {
#pragma unroll
      for (int ks = 0; ks < 4; ++ks) {
        bf16x8 afq = *(const bf16x8*)(sQ + (wave * 16 + r) * 136 + ks * 32 + quad * 8);
        bf16x8 bs = *(const bf16x8*)(U1 + (j * 16 + r) * 128 + ks * 32 + quad * 8);
        acc2 = __builtin_amdgcn_mfma_f32_16x16x32_bf16(afq, bs, acc2, 0, 0, 0);
      }
    }
#pragma unroll
    for (int reg = 0; reg < 4; ++reg) {
      int t = wave * 16 + quad * 4 + reg;
      int v = j * 16 + r;
      O[rowbase + (size_t)t * 1024 + v] = f2bf(acc2[reg]);
    }
  }
}

__global__ __launch_bounds__(256) void hgru_rmsnorm(const u16* __restrict__ O,
                                                    const float* __restrict__ w,
                                                    u16* __restrict__ On) {
  __shared__ float sred[4];
  const int row = blockIdx.x, tid = threadIdx.x;
  const size_t base = (size_t)row * 1024;
  float vals[4];
  float ss = 0.f;
#pragma unroll
  for (int k = 0; k < 4; ++k) {
    float v = bf2f(O[base + k * 256 + tid]);
    vals[k] = v;
    ss += v * v;
  }
#pragma unroll
  for (int m = 32; m >= 1; m >>= 1) ss += __shfl_xor(ss, m);
  if ((tid & 63) == 0) sred[tid >> 6] = ss;
  __syncthreads();
  float tot = sred[0] + sred[1] + sred[2] + sred[3];
  float scale = rsqrtf(tot * (1.f / 1024.f) + 1e-6f);
#pragma unroll
  for (int k = 0; k < 4; ++k)
    On[base + k * 256 + tid] = f2bf(vals[k] * scale * w[k * 256 + tid]);
}

__global__ __launch_bounds__(256) void hgru_gemm_out(const u16* __restrict__ Ab,
                                                     const u16* __restrict__ Wob,
                                                     float* __restrict__ out) {
  __shared__ alignas(16) u16 smem[16384];
  const u16* Ag = Ab + (size_t)blockIdx.x * 128 * 1024;
  const u16* Bg = Wob + (size_t)blockIdx.y * 128 * 1024;
  f32x4 acc[4][4] = {};
  gemm128_core(Ag, Bg, smem, acc);
  const int tid = threadIdx.x, lane = tid & 63, wave = tid >> 6;
  const int wm = (wave & 1) * 64, wn = (wave >> 1) * 64;
  const int r = lane & 15, quad = lane >> 4;
#pragma unroll
  for (int i = 0; i < 4; ++i)
#pragma unroll
    for (int j = 0; j < 4; ++j)
#pragma unroll
      for (int reg = 0; reg < 4; ++reg) {
        int m = blockIdx.x * 128 + wm + i * 16 + quad * 4 + reg;
        int n = blockIdx.y * 128 + wn + j * 16 + r;
        out[(size_t)m * 1024 + n] = acc[i][j][reg];
      }
}

// ---------------------------------------------------------------------------
extern "C" void kernel_launch(void* const* d_in, const int* in_sizes, int n_in,
                              void* d_out, int out_size, void* d_ws, size_t ws_size,
                              hipStream_t stream) {
  const float* x  = (const float*)d_in[0];
  const float* Wq = (const float*)d_in[1];
  const float* Wk = (const float*)d_in[2];
  const float* Wv = (const float*)d_in[3];
  const float* Wo = (const float*)d_in[4];
  const float* nw = (const float*)d_in[5];
  float* out = (float*)d_out;
  char* ws = (char*)d_ws;

  u16* Xb   = (u16*)(ws + 0);            // 16 MB (reused as normed output later)
  u16* Wqb  = (u16*)(ws + 16777216);
  u16* Wkb  = (u16*)(ws + 18874368);
  u16* Wvb  = (u16*)(ws + 20971520);
  u16* Wob  = (u16*)(ws + 23068672);
  u16* Qb   = (u16*)(ws + 25165824);     // q -> qhat in place (phaseA)
  u16* Kb   = (u16*)(ws + 41943040);     // k -> ktilde in place (phaseA)
  u16* Vb   = (u16*)(ws + 58720256);
  u16* SU   = (u16*)(ws + 75497472);     // 32 MB  [1024][128][128] U^T bf16
  u16* Obf  = (u16*)(ws + 109051904);    // 16 MB
  u16* On   = Xb;

  cast_f32_bf16<<<8192, 256, 0, stream>>>(x, Xb, 2097152);
  dim3 gw(1024, 4);
  cast_w4<<<gw, 256, 0, stream>>>(Wq, Wk, Wv, Wo, Wqb, Wkb, Wvb, Wob);

  dim3 gq(64, 24);
  hgru_gemm_qkv<<<gq, 256, 0, stream>>>(Xb, Wqb, Wkb, Wvb, Qb, Kb, Vb);
  hgru_phaseA<<<1024, 256, 0, stream>>>(Qb, Kb, Vb, SU);
  hgru_phaseC<<<1024, 256, 0, stream>>>(Qb, Kb, Vb, SU, Obf);
  hgru_rmsnorm<<<8192, 256, 0, stream>>>(Obf, nw, On);
  dim3 go(64, 8);
  hgru_gemm_out<<<go, 256, 0, stream>>>(On, Wob, out);
}